// Round 1
// baseline (480.378 us; speedup 1.0000x reference)
//
#include <hip/hip_runtime.h>

// Sparsemax along last axis of (4, 4096, 4096) fp32.
// One block per row; row lives in registers (16 floats/thread).
// tau found by Newton on f(tau) = sum(relu(z - tau)) - 1 (convex,
// piecewise-linear, finite convergence from tau0 = z_max - 1).

constexpr int D = 4096;
constexpr int BLOCK = 256;
constexpr int CHUNKS = D / (BLOCK * 4);   // 4 float4 per thread
constexpr int NEWTON_ITERS = 16;          // converges in ~6-8 for Gaussian rows; extra iters idempotent

__global__ __launch_bounds__(BLOCK) void sparsemax_kernel(
    const float* __restrict__ in, float* __restrict__ out) {
  __shared__ float smS[4];
  __shared__ float smK[4];
  __shared__ float sB[1];

  const long long row = blockIdx.x;
  const float4* __restrict__ x4 =
      reinterpret_cast<const float4*>(in + row * (long long)D);
  float4* __restrict__ y4 = reinterpret_cast<float4*>(out + row * (long long)D);

  const int t = threadIdx.x;
  const int wave = t >> 6;
  const int lane = t & 63;

  // ---- load row into registers (coalesced: lane-contiguous float4) ----
  float4 v[CHUNKS];
#pragma unroll
  for (int c = 0; c < CHUNKS; c++) v[c] = x4[t + c * BLOCK];

  // ---- row max ----
  float m = -INFINITY;
#pragma unroll
  for (int c = 0; c < CHUNKS; c++)
    m = fmaxf(m, fmaxf(fmaxf(v[c].x, v[c].y), fmaxf(v[c].z, v[c].w)));
#pragma unroll
  for (int o = 32; o > 0; o >>= 1) m = fmaxf(m, __shfl_down(m, o));
  if (lane == 0) smS[wave] = m;
  __syncthreads();
  if (t == 0)
    sB[0] = fmaxf(fmaxf(smS[0], smS[1]), fmaxf(smS[2], smS[3]));
  __syncthreads();
  m = sB[0];

  // ---- shift: z = x - max (z_max == 0) ----
#pragma unroll
  for (int c = 0; c < CHUNKS; c++) {
    v[c].x -= m; v[c].y -= m; v[c].z -= m; v[c].w -= m;
  }

  // ---- Newton on f(tau) = sum(relu(z - tau)) - 1 ----
  // tau0 = -1 (== z_max - 1): f(tau0) >= 0; Newton is monotone increasing,
  // never overshoots (f convex), lands exactly on root when active set fixes.
  float tau = -1.0f;
  for (int it = 0; it < NEWTON_ITERS; it++) {
    float S = 0.0f, K = 0.0f;
#pragma unroll
    for (int c = 0; c < CHUNKS; c++) {
      float z;
      z = v[c].x; if (z > tau) { S += z; K += 1.0f; }
      z = v[c].y; if (z > tau) { S += z; K += 1.0f; }
      z = v[c].z; if (z > tau) { S += z; K += 1.0f; }
      z = v[c].w; if (z > tau) { S += z; K += 1.0f; }
    }
#pragma unroll
    for (int o = 32; o > 0; o >>= 1) {
      S += __shfl_down(S, o);
      K += __shfl_down(K, o);
    }
    if (lane == 0) { smS[wave] = S; smK[wave] = K; }
    __syncthreads();
    if (t == 0) {
      float St = smS[0] + smS[1] + smS[2] + smS[3];
      float Kt = smK[0] + smK[1] + smK[2] + smK[3];
      // Kt >= 1 always: z_max = 0 > tau (tau <= root < 0)
      sB[0] = (St - 1.0f) / Kt;
    }
    __syncthreads();
    tau = sB[0];
  }

  // ---- write p = max(z - tau, 0), coalesced float4 ----
#pragma unroll
  for (int c = 0; c < CHUNKS; c++) {
    float4 o;
    o.x = fmaxf(v[c].x - tau, 0.0f);
    o.y = fmaxf(v[c].y - tau, 0.0f);
    o.z = fmaxf(v[c].z - tau, 0.0f);
    o.w = fmaxf(v[c].w - tau, 0.0f);
    y4[t + c * BLOCK] = o;
  }
}

extern "C" void kernel_launch(void* const* d_in, const int* in_sizes, int n_in,
                              void* d_out, int out_size, void* d_ws, size_t ws_size,
                              hipStream_t stream) {
  const float* in = (const float*)d_in[0];
  float* out = (float*)d_out;
  const int rows = in_sizes[0] / D;  // 4 * 4096 = 16384
  sparsemax_kernel<<<rows, BLOCK, 0, stream>>>(in, out);
}

// Round 2
// 432.869 us; speedup vs baseline: 1.1098x; 1.1098x over previous
//
#include <hip/hip_runtime.h>

// Sparsemax along last axis of (4, 4096, 4096) fp32.
// One block per row; row lives in registers (16 floats/thread).
// tau solves sum(relu(x - tau)) = 1 via Newton from tau0 = max - 1
// (monotone, finite convergence). Only elements with x > max-1 can ever
// be active (tau >= max-1), so they are compacted into LDS (~14/row for
// Gaussian data) and ONE wave runs Newton on the tiny set. Block-wide
// register Newton is the (correctness-only) fallback if > CAP candidates.

constexpr int D = 4096;
constexpr int BLOCK = 256;
constexpr int CHUNKS = D / (BLOCK * 4);   // 4 float4 per thread
constexpr int NEWTON_ITERS = 16;          // converges in ~6-8; extras idempotent
constexpr int CAP = 1024;                 // candidate capacity (4 KB LDS)

__global__ __launch_bounds__(BLOCK) void sparsemax_kernel(
    const float* __restrict__ in, float* __restrict__ out) {
  __shared__ float smax[4];
  __shared__ float smS[4], smK[4];
  __shared__ float sB;
  __shared__ int scnt;
  __shared__ float cand[CAP];

  const long long row = blockIdx.x;
  const float4* __restrict__ x4 =
      reinterpret_cast<const float4*>(in + row * (long long)D);
  float4* __restrict__ y4 = reinterpret_cast<float4*>(out + row * (long long)D);

  const int t = threadIdx.x;
  const int wave = t >> 6;
  const int lane = t & 63;

  // ---- load row into registers (coalesced float4) ----
  float4 v[CHUNKS];
#pragma unroll
  for (int c = 0; c < CHUNKS; c++) v[c] = x4[t + c * BLOCK];

  // ---- row max (butterfly -> all lanes) ----
  float m = -INFINITY;
#pragma unroll
  for (int c = 0; c < CHUNKS; c++)
    m = fmaxf(m, fmaxf(fmaxf(v[c].x, v[c].y), fmaxf(v[c].z, v[c].w)));
#pragma unroll
  for (int o = 32; o > 0; o >>= 1) m = fmaxf(m, __shfl_xor(m, o));
  if (lane == 0) smax[wave] = m;
  if (t == 0) scnt = 0;
  __syncthreads();
  m = fmaxf(fmaxf(smax[0], smax[1]), fmaxf(smax[2], smax[3]));
  const float thr = m - 1.0f;  // tau0; no x <= thr can ever be active

  // ---- compact candidates (x > thr) into LDS ----
  int lc = 0;
#pragma unroll
  for (int c = 0; c < CHUNKS; c++) {
    lc += (v[c].x > thr) + (v[c].y > thr) + (v[c].z > thr) + (v[c].w > thr);
  }
  if (lc > 0) {
    int base = atomicAdd(&scnt, lc);
#pragma unroll
    for (int c = 0; c < CHUNKS; c++) {
      float z;
      z = v[c].x; if (z > thr) { if (base < CAP) cand[base] = z; base++; }
      z = v[c].y; if (z > thr) { if (base < CAP) cand[base] = z; base++; }
      z = v[c].z; if (z > thr) { if (base < CAP) cand[base] = z; base++; }
      z = v[c].w; if (z > thr) { if (base < CAP) cand[base] = z; base++; }
    }
  }
  __syncthreads();
  const int n = scnt;

  if (n <= CAP) {
    // ---- Newton on the tiny candidate set, wave 0 only ----
    if (wave == 0) {
      float tau = thr;
      if (n <= 64) {
        // hot path: one candidate per lane, in-register
        const float sentinel = thr - 1.0f;  // never > tau (tau >= thr)
        float z = (lane < n) ? cand[lane] : sentinel;
        for (int it = 0; it < NEWTON_ITERS; it++) {
          float S = 0.0f, K = 0.0f;
          if (z > tau) { S = z; K = 1.0f; }
#pragma unroll
          for (int o = 32; o > 0; o >>= 1) {
            S += __shfl_xor(S, o);
            K += __shfl_xor(K, o);
          }
          tau = (S - 1.0f) / K;  // K >= 1: x_max = m > tau always
        }
      } else {
        for (int it = 0; it < NEWTON_ITERS; it++) {
          float S = 0.0f, K = 0.0f;
          for (int i = lane; i < n; i += 64) {
            float z = cand[i];
            if (z > tau) { S += z; K += 1.0f; }
          }
#pragma unroll
          for (int o = 32; o > 0; o >>= 1) {
            S += __shfl_xor(S, o);
            K += __shfl_xor(K, o);
          }
          tau = (S - 1.0f) / K;
        }
      }
      if (lane == 0) sB = tau;
    }
  } else {
    // ---- fallback: block-wide Newton over registers (never for Gaussian) ----
    float tau = thr;
    for (int it = 0; it < NEWTON_ITERS; it++) {
      float S = 0.0f, K = 0.0f;
#pragma unroll
      for (int c = 0; c < CHUNKS; c++) {
        float z;
        z = v[c].x; if (z > tau) { S += z; K += 1.0f; }
        z = v[c].y; if (z > tau) { S += z; K += 1.0f; }
        z = v[c].z; if (z > tau) { S += z; K += 1.0f; }
        z = v[c].w; if (z > tau) { S += z; K += 1.0f; }
      }
#pragma unroll
      for (int o = 32; o > 0; o >>= 1) {
        S += __shfl_xor(S, o);
        K += __shfl_xor(K, o);
      }
      if (lane == 0) { smS[wave] = S; smK[wave] = K; }
      __syncthreads();
      float St = smS[0] + smS[1] + smS[2] + smS[3];
      float Kt = smK[0] + smK[1] + smK[2] + smK[3];
      tau = (St - 1.0f) / Kt;
      __syncthreads();
    }
    if (t == 0) sB = tau;
  }
  __syncthreads();
  const float tau = sB;

  // ---- write p = max(x - tau, 0), coalesced float4 ----
#pragma unroll
  for (int c = 0; c < CHUNKS; c++) {
    float4 o;
    o.x = fmaxf(v[c].x - tau, 0.0f);
    o.y = fmaxf(v[c].y - tau, 0.0f);
    o.z = fmaxf(v[c].z - tau, 0.0f);
    o.w = fmaxf(v[c].w - tau, 0.0f);
    y4[t + c * BLOCK] = o;
  }
}

extern "C" void kernel_launch(void* const* d_in, const int* in_sizes, int n_in,
                              void* d_out, int out_size, void* d_ws, size_t ws_size,
                              hipStream_t stream) {
  const float* in = (const float*)d_in[0];
  float* out = (float*)d_out;
  const int rows = in_sizes[0] / D;  // 16384
  sparsemax_kernel<<<rows, BLOCK, 0, stream>>>(in, out);
}